// Round 1
// baseline (770.687 us; speedup 1.0000x reference)
//
#include <hip/hip_runtime.h>

typedef unsigned short u16;
typedef unsigned int u32;
typedef __bf16 bf16x8 __attribute__((ext_vector_type(8)));
typedef float f32x4 __attribute__((ext_vector_type(4)));
typedef u16 u16x4 __attribute__((ext_vector_type(4)));

#define T_TOK 8192
#define HDIM 1024
#define IDIM 2816
#define NEXP 8
#define NPAIR (T_TOK * 2)     // 16384 (token,slot) pairs
#define MAXRB 136             // max padded 128-row blocks: 16384/128 + 7

// workspace layout (bytes)
#define XB_OFF   (131072u)                      // X as bf16        [8192][1024]
#define W13T_OFF (XB_OFF + 16777216u)           // w13^T bf16       [E][5632][1024]
#define W2T_OFF  (W13T_OFF + 92274688u)         // w2^T bf16        [E][1024][2816]
#define H_OFF    (W2T_OFF + 46137344u)          // h bf16 (padded)  [17408][2816]
#define WS_NEED  ((size_t)H_OFF + 98041856u)    // ~254 MB

__device__ __forceinline__ u16 f2bf(float f) {
  u32 u = __builtin_bit_cast(u32, f);
  u32 r = u + 0x7fffu + ((u >> 16) & 1u);   // RNE
  return (u16)(r >> 16);
}

#define GLD16(g, l) __builtin_amdgcn_global_load_lds( \
    (const __attribute__((address_space(1))) void*)(g), \
    (__attribute__((address_space(3))) void*)(l), 16, 0, 0)

// ---------------- routing ----------------
__global__ void init_meta(int* meta) {
  if (threadIdx.x < 16) meta[threadIdx.x] = 0;  // counts[8], cursors[8]
}

__global__ void count_k(const int* __restrict__ routing, int* __restrict__ meta) {
  int i = blockIdx.x * 256 + threadIdx.x;
  if (i < NPAIR) atomicAdd(&meta[routing[i]], 1);
}

// meta: [0..7] counts, [8..15] cursors, [16..23] startRow, [24] totalRB, [32..167] rbExpert
__global__ void scan_fill(int* __restrict__ meta, int* __restrict__ pairs) {
  if (threadIdx.x == 0) {
    int rb = 0;
    for (int e = 0; e < NEXP; ++e) {
      meta[16 + e] = rb * 128;
      int nrb = (meta[e] + 127) >> 7;
      for (int i = 0; i < nrb; ++i) meta[32 + rb + i] = e;
      rb += nrb;
    }
    meta[24] = rb;
  }
  for (int i = threadIdx.x; i < MAXRB * 128; i += 256) pairs[i] = -1;
}

__global__ void scatter_k(const int* __restrict__ routing, int* __restrict__ meta,
                          int* __restrict__ pairs) {
  int i = blockIdx.x * 256 + threadIdx.x;
  if (i < NPAIR) {
    int e = routing[i];
    int pos = atomicAdd(&meta[8 + e], 1);
    pairs[meta[16 + e] + pos] = i;   // i = token*2 + slot, also flat rw index
  }
}

// ---------------- converts ----------------
__global__ void conv_x(const float* __restrict__ in, u16* __restrict__ out) {
  int i = blockIdx.x * 256 + threadIdx.x;     // grid covers exactly T*H/4
  float4 v = ((const float4*)in)[i];
  u16x4 o = { f2bf(v.x), f2bf(v.y), f2bf(v.z), f2bf(v.w) };
  ((u16x4*)out)[i] = o;
}

// out[c][r] = bf16(in[r][c]); per-expert slab via blockIdx.z
__global__ void transpose_cvt(const float* __restrict__ in, u16* __restrict__ out,
                              int R, int C) {
  __shared__ float tile[64][65];
  size_t base = (size_t)blockIdx.z * (size_t)R * (size_t)C;
  in += base; out += base;
  int t = threadIdx.x, tc = t & 63, tr = t >> 6;
  int r0 = blockIdx.y * 64, c0 = blockIdx.x * 64;
#pragma unroll
  for (int p = 0; p < 16; ++p) {
    int r = p * 4 + tr;
    tile[r][tc] = in[(size_t)(r0 + r) * C + c0 + tc];
  }
  __syncthreads();
#pragma unroll
  for (int p = 0; p < 16; ++p) {
    int oc = p * 4 + tr;
    out[(size_t)(c0 + oc) * R + r0 + tc] = f2bf(tile[tc][oc]);
  }
}

// ---------------- GEMM1: gu = X@w13 (gate+up), h = silu(g)*u*rw ----------------
__global__ __launch_bounds__(256, 2) void gemm1_k(
    const u16* __restrict__ Xb, const u16* __restrict__ W13T,
    const int* __restrict__ pairs, const int* __restrict__ meta,
    const float* __restrict__ rwf, u16* __restrict__ Hb) {
  const int rb = blockIdx.y;
  if (rb >= meta[24]) return;
  const int e = meta[32 + rb];
  const int n0 = blockIdx.x * 128;
  const int tid = threadIdx.x, lane = tid & 63, w = tid >> 6;
  const int wrow = w >> 1, wcol = w & 1;
  const int rbBase = rb * 128;

  __shared__ u16 As[2][128 * 32];
  __shared__ u16 Bgs[2][128 * 32];
  __shared__ u16 Bus[2][128 * 32];

  // staging: per wave 2 chunks of 64 lanes x 16B per tile; chunk c -> row c>>2, kseg c&3
  const int c0 = w * 128 + lane;
  const int r0 = c0 >> 2, s0 = c0 & 3;
  int p0 = pairs[rbBase + r0];
  int p1 = pairs[rbBase + r0 + 16];
  const u16* aP0 = Xb + (size_t)(p0 < 0 ? 0 : (p0 >> 1)) * HDIM + s0 * 8;
  const u16* aP1 = Xb + (size_t)(p1 < 0 ? 0 : (p1 >> 1)) * HDIM + s0 * 8;
  const u16* wB = W13T + (size_t)e * (2 * IDIM) * HDIM;
  const u16* gP0 = wB + (size_t)(n0 + r0) * HDIM + s0 * 8;
  const u16* gP1 = gP0 + 16 * HDIM;
  const u16* uP0 = wB + (size_t)(IDIM + n0 + r0) * HDIM + s0 * 8;
  const u16* uP1 = uP0 + 16 * HDIM;
  const int lb0 = __builtin_amdgcn_readfirstlane(w * 2048);
  const int lb1 = lb0 + 1024;

  f32x4 accG[4][4], accU[4][4];
  const f32x4 fz = {0.f, 0.f, 0.f, 0.f};
#pragma unroll
  for (int i = 0; i < 4; ++i)
#pragma unroll
    for (int j = 0; j < 4; ++j) { accG[i][j] = fz; accU[i][j] = fz; }

#define STAGE1(buf, kk) do { \
    GLD16(aP0 + (kk), (char*)As[buf] + lb0);  GLD16(aP1 + (kk), (char*)As[buf] + lb1);  \
    GLD16(gP0 + (kk), (char*)Bgs[buf] + lb0); GLD16(gP1 + (kk), (char*)Bgs[buf] + lb1); \
    GLD16(uP0 + (kk), (char*)Bus[buf] + lb0); GLD16(uP1 + (kk), (char*)Bus[buf] + lb1); \
  } while (0)

  STAGE1(0, 0);
  __syncthreads();
  int cur = 0;
  const int aoff = (lane & 15) * 32 + (lane >> 4) * 8;  // u16 units
  for (int t = 0; t < 32; ++t) {
    if (t < 31) STAGE1(cur ^ 1, (t + 1) * 32);
    const u16* Ab = As[cur] + (wrow * 64) * 32 + aoff;
    const u16* Gb = Bgs[cur] + (wcol * 64) * 32 + aoff;
    const u16* Ub = Bus[cur] + (wcol * 64) * 32 + aoff;
    bf16x8 aF[4], gF[4], uF[4];
#pragma unroll
    for (int f = 0; f < 4; ++f) {
      aF[f] = *(const bf16x8*)(Ab + f * 16 * 32);
      gF[f] = *(const bf16x8*)(Gb + f * 16 * 32);
      uF[f] = *(const bf16x8*)(Ub + f * 16 * 32);
    }
#pragma unroll
    for (int fm = 0; fm < 4; ++fm)
#pragma unroll
      for (int fn = 0; fn < 4; ++fn) {
        accG[fm][fn] = __builtin_amdgcn_mfma_f32_16x16x32_bf16(aF[fm], gF[fn], accG[fm][fn], 0, 0, 0);
        accU[fm][fn] = __builtin_amdgcn_mfma_f32_16x16x32_bf16(aF[fm], uF[fn], accU[fm][fn], 0, 0, 0);
      }
    __syncthreads();
    cur ^= 1;
  }
#undef STAGE1

  // epilogue: C/D layout col=lane&15, row=(lane>>4)*4+j  [m89-verified]
  const int cc = lane & 15, ct = lane >> 4;
#pragma unroll
  for (int fm = 0; fm < 4; ++fm) {
#pragma unroll
    for (int j = 0; j < 4; ++j) {
      int r = wrow * 64 + fm * 16 + ct * 4 + j;
      int pr = rbBase + r;
      int pair = pairs[pr];
      float rw = pair >= 0 ? rwf[pair] : 0.f;   // pad rows -> h = 0
      u16* hrow = Hb + (size_t)pr * IDIM + n0 + wcol * 64 + cc;
#pragma unroll
      for (int fn = 0; fn < 4; ++fn) {
        float g = accG[fm][fn][j], u = accU[fm][fn][j];
        float s = g / (1.f + __expf(-g));
        hrow[fn * 16] = f2bf(s * u * rw);
      }
    }
  }
}

// ---------------- GEMM2: out[tok] += h @ w2 ----------------
__global__ __launch_bounds__(256, 2) void gemm2_k(
    const u16* __restrict__ Hb, const u16* __restrict__ W2T,
    const int* __restrict__ pairs, const int* __restrict__ meta,
    float* __restrict__ out) {
  const int rb = blockIdx.y;
  if (rb >= meta[24]) return;
  const int e = meta[32 + rb];
  const int n0 = blockIdx.x * 128;
  const int tid = threadIdx.x, lane = tid & 63, w = tid >> 6;
  const int wrow = w >> 1, wcol = w & 1;
  const int rbBase = rb * 128;

  __shared__ u16 As[2][128 * 32];
  __shared__ u16 Bs[2][128 * 32];

  const int c0 = w * 128 + lane;
  const int r0 = c0 >> 2, s0 = c0 & 3;
  const u16* aP0 = Hb + (size_t)(rbBase + r0) * IDIM + s0 * 8;
  const u16* aP1 = aP0 + (size_t)16 * IDIM;
  const u16* bP0 = W2T + (size_t)e * HDIM * IDIM + (size_t)(n0 + r0) * IDIM + s0 * 8;
  const u16* bP1 = bP0 + (size_t)16 * IDIM;
  const int lb0 = __builtin_amdgcn_readfirstlane(w * 2048);
  const int lb1 = lb0 + 1024;

  f32x4 acc[4][4];
  const f32x4 fz = {0.f, 0.f, 0.f, 0.f};
#pragma unroll
  for (int i = 0; i < 4; ++i)
#pragma unroll
    for (int j = 0; j < 4; ++j) acc[i][j] = fz;

#define STAGE2(buf, kk) do { \
    GLD16(aP0 + (kk), (char*)As[buf] + lb0); GLD16(aP1 + (kk), (char*)As[buf] + lb1); \
    GLD16(bP0 + (kk), (char*)Bs[buf] + lb0); GLD16(bP1 + (kk), (char*)Bs[buf] + lb1); \
  } while (0)

  STAGE2(0, 0);
  __syncthreads();
  int cur = 0;
  const int aoff = (lane & 15) * 32 + (lane >> 4) * 8;
  for (int t = 0; t < 88; ++t) {
    if (t < 87) STAGE2(cur ^ 1, (t + 1) * 32);
    const u16* Ab = As[cur] + (wrow * 64) * 32 + aoff;
    const u16* Bb = Bs[cur] + (wcol * 64) * 32 + aoff;
    bf16x8 aF[4], bF[4];
#pragma unroll
    for (int f = 0; f < 4; ++f) {
      aF[f] = *(const bf16x8*)(Ab + f * 16 * 32);
      bF[f] = *(const bf16x8*)(Bb + f * 16 * 32);
    }
#pragma unroll
    for (int fm = 0; fm < 4; ++fm)
#pragma unroll
      for (int fn = 0; fn < 4; ++fn)
        acc[fm][fn] = __builtin_amdgcn_mfma_f32_16x16x32_bf16(aF[fm], bF[fn], acc[fm][fn], 0, 0, 0);
    __syncthreads();
    cur ^= 1;
  }
#undef STAGE2

  const int cc = lane & 15, ct = lane >> 4;
#pragma unroll
  for (int fm = 0; fm < 4; ++fm) {
#pragma unroll
    for (int j = 0; j < 4; ++j) {
      int r = wrow * 64 + fm * 16 + ct * 4 + j;
      int pair = pairs[rbBase + r];
      if (pair >= 0) {
        float* orow = out + (size_t)(pair >> 1) * HDIM + n0 + wcol * 64 + cc;
#pragma unroll
        for (int fn = 0; fn < 4; ++fn) atomicAdd(orow + fn * 16, acc[fm][fn][j]);
      }
    }
  }
}

extern "C" void kernel_launch(void* const* d_in, const int* in_sizes, int n_in,
                              void* d_out, int out_size, void* d_ws, size_t ws_size,
                              hipStream_t stream) {
  const float* X = (const float*)d_in[0];
  const int* routing = (const int*)d_in[1];
  const float* rwf = (const float*)d_in[2];
  const float* w13 = (const float*)d_in[3];
  const float* w2 = (const float*)d_in[4];
  float* out = (float*)d_out;
  char* ws = (char*)d_ws;

  hipMemsetAsync(d_out, 0, (size_t)T_TOK * HDIM * sizeof(float), stream);
  if (ws_size < WS_NEED) return;  // signals ws too small: out stays 0 -> err == max|ref| ~ 4.9

  int* meta = (int*)ws;
  int* pairs = (int*)(ws + 1024);
  u16* Xb = (u16*)(ws + XB_OFF);
  u16* W13T = (u16*)(ws + W13T_OFF);
  u16* W2T = (u16*)(ws + W2T_OFF);
  u16* Hb = (u16*)(ws + H_OFF);

  init_meta<<<1, 64, 0, stream>>>(meta);
  count_k<<<NPAIR / 256, 256, 0, stream>>>(routing, meta);
  scan_fill<<<1, 256, 0, stream>>>(meta, pairs);
  scatter_k<<<NPAIR / 256, 256, 0, stream>>>(routing, meta, pairs);
  conv_x<<<(T_TOK * HDIM / 4) / 256, 256, 0, stream>>>(X, Xb);
  transpose_cvt<<<dim3(5632 / 64, 1024 / 64, NEXP), 256, 0, stream>>>(w13, W13T, 1024, 5632);
  transpose_cvt<<<dim3(1024 / 64, 2816 / 64, NEXP), 256, 0, stream>>>(w2, W2T, 2816, 1024);
  gemm1_k<<<dim3(IDIM / 128, MAXRB), 256, 0, stream>>>(Xb, W13T, pairs, meta, rwf, Hb);
  gemm2_k<<<dim3(HDIM / 128, MAXRB), 256, 0, stream>>>(Hb, W2T, pairs, meta, out);
}

// Round 2
// 653.236 us; speedup vs baseline: 1.1798x; 1.1798x over previous
//
#include <hip/hip_runtime.h>

typedef unsigned short u16;
typedef unsigned int u32;
typedef __bf16 bf16x8 __attribute__((ext_vector_type(8)));
typedef float f32x4 __attribute__((ext_vector_type(4)));
typedef u16 u16x4 __attribute__((ext_vector_type(4)));

#define T_TOK 8192
#define HDIM 1024
#define IDIM 2816
#define NEXP 8
#define NPAIR (T_TOK * 2)
#define MAXRB 71   // provable max: sum_e ceil(c_e/256) <= 63+8

// workspace layout (bytes)
#define XB_OFF   (131072u)                       // X bf16 [8192][1024]
#define W13T_OFF (XB_OFF + 16777216u)            // w13^T bf16 [E][5632][1024]
#define W2T_OFF  (W13T_OFF + 92274688u)          // w2^T bf16 [E][1024][2816]
#define H_OFF    (W2T_OFF + 46137344u)           // h bf16 [71*256][2816]
#define WS_NEED  ((size_t)H_OFF + 102367232u)    // ~257.7 MB

__device__ __forceinline__ u16 f2bf(float f) {
  u32 u = __builtin_bit_cast(u32, f);
  u32 r = u + 0x7fffu + ((u >> 16) & 1u);
  return (u16)(r >> 16);
}

#define GLD16(g, l) __builtin_amdgcn_global_load_lds( \
    (const __attribute__((address_space(1))) void*)(g), \
    (__attribute__((address_space(3))) void*)(l), 16, 0, 0)

#define WAITVM(N) asm volatile("s_waitcnt vmcnt(" #N ")" ::: "memory")

__device__ __forceinline__ void pbar() {
  __builtin_amdgcn_sched_barrier(0);
  asm volatile("" ::: "memory");
  __builtin_amdgcn_s_barrier();
  asm volatile("" ::: "memory");
  __builtin_amdgcn_sched_barrier(0);
}

// ---------------- routing ----------------
__global__ void init_meta(int* meta) {
  if (threadIdx.x < 16) meta[threadIdx.x] = 0;
}

__global__ void count_k(const int* __restrict__ routing, int* __restrict__ meta) {
  int i = blockIdx.x * 256 + threadIdx.x;
  if (i < NPAIR) atomicAdd(&meta[routing[i]], 1);
}

// meta: [0..7] counts, [8..15] cursors, [16..23] startRow, [24] totalRB, [32..102] rbExpert
__global__ void scan_fill(int* __restrict__ meta, int* __restrict__ pairs) {
  if (threadIdx.x == 0) {
    int rb = 0;
    for (int e = 0; e < NEXP; ++e) {
      meta[16 + e] = rb * 256;
      int nrb = (meta[e] + 255) >> 8;
      for (int i = 0; i < nrb; ++i) meta[32 + rb + i] = e;
      rb += nrb;
    }
    meta[24] = rb;
  }
  for (int i = threadIdx.x; i < MAXRB * 256; i += 256) pairs[i] = -1;
}

__global__ void scatter_k(const int* __restrict__ routing, int* __restrict__ meta,
                          int* __restrict__ pairs) {
  int i = blockIdx.x * 256 + threadIdx.x;
  if (i < NPAIR) {
    int e = routing[i];
    int pos = atomicAdd(&meta[8 + e], 1);
    pairs[meta[16 + e] + pos] = i;
  }
}

// ---------------- converts ----------------
__global__ void conv_x(const float* __restrict__ in, u16* __restrict__ out) {
  int i = blockIdx.x * 256 + threadIdx.x;
  float4 v = ((const float4*)in)[i];
  u16x4 o = { f2bf(v.x), f2bf(v.y), f2bf(v.z), f2bf(v.w) };
  ((u16x4*)out)[i] = o;
}

__global__ void transpose_cvt(const float* __restrict__ in, u16* __restrict__ out,
                              int R, int C) {
  __shared__ float tile[64][65];
  size_t base = (size_t)blockIdx.z * (size_t)R * (size_t)C;
  in += base; out += base;
  int t = threadIdx.x, tc = t & 63, tr = t >> 6;
  int r0 = blockIdx.y * 64, c0 = blockIdx.x * 64;
#pragma unroll
  for (int p = 0; p < 16; ++p) {
    int r = p * 4 + tr;
    tile[r][tc] = in[(size_t)(r0 + r) * C + c0 + tc];
  }
  __syncthreads();
#pragma unroll
  for (int p = 0; p < 16; ++p) {
    int oc = p * 4 + tr;
    out[(size_t)(c0 + oc) * R + r0 + tc] = f2bf(tile[tc][oc]);
  }
}

// ======================= GEMM1 (8-phase, dual-B gate+up) =======================
// BM=256, BK=64, gate 128 + up 128 cols per block; 8 waves = 4M x 2N; per-wave 64x64 per matrix.
__global__ __launch_bounds__(512, 2) void gemm1_k(
    const u16* __restrict__ Xb, const u16* __restrict__ W13T,
    const int* __restrict__ pairs, const int* __restrict__ meta,
    const float* __restrict__ rwf, u16* __restrict__ Hb) {
  // XCD swizzle: nwg = 22*71 = 1562, q=195, r=2; group n-panels per XCD
  int lin = blockIdx.x + 22 * blockIdx.y;
  int xcd = lin & 7, slot = lin >> 3;
  int flat = (xcd < 2) ? xcd * 196 + slot : 392 + (xcd - 2) * 195 + slot;
  int bx = flat / 71, rb = flat % 71;
  if (rb >= meta[24]) return;
  const int e = meta[32 + rb];
  const int bn0 = bx * 128;
  const int tid = threadIdx.x, lane = tid & 63, w = tid >> 6;
  const int wr = w >> 1, wc = w & 1;
  const int rowBase = rb * 256;

  __shared__ __align__(16) u16 lds[65536];  // 128 KiB: A 2x32K | Bg 2x16K | Bu 2x16K
  char* const lb = (char*)lds;

  // ---- staging setup (T2: inverse-swizzled global source, linear LDS dest) ----
  const int sr = tid >> 3;                   // row within 64-row group
  const int swk = ((tid & 7) << 4) ^ ((sr & 7) << 4);  // swizzled byte-in-row
  const u16* aS[4];
#pragma unroll
  for (int h = 0; h < 2; ++h)
#pragma unroll
    for (int j = 0; j < 2; ++j) {
      int pr = pairs[rowBase + h * 128 + j * 64 + sr];
      int tok = pr < 0 ? 0 : (pr >> 1);
      aS[h * 2 + j] = Xb + (size_t)tok * HDIM + (swk >> 1);
    }
  const u16* wBase = W13T + (size_t)e * (2 * IDIM) * HDIM;
  const u16* gS[2]; const u16* uS[2];
#pragma unroll
  for (int j = 0; j < 2; ++j) {
    int r = j * 64 + sr;
    gS[j] = wBase + (size_t)(bn0 + r) * HDIM + (swk >> 1);
    uS[j] = wBase + (size_t)(IDIM + bn0 + r) * HDIM + (swk >> 1);
  }

#define STG_A(b, h, kt) { GLD16(aS[(h)*2+0] + (kt)*64, lb + (b)*32768 + (h)*16384 + tid*16); \
                          GLD16(aS[(h)*2+1] + (kt)*64, lb + (b)*32768 + (h)*16384 + 8192 + tid*16); }
#define STG_G(b, kt)    { GLD16(gS[0] + (kt)*64, lb + 65536 + (b)*16384 + tid*16); \
                          GLD16(gS[1] + (kt)*64, lb + 65536 + (b)*16384 + 8192 + tid*16); }
#define STG_U(b, kt)    { GLD16(uS[0] + (kt)*64, lb + 98304 + (b)*16384 + tid*16); \
                          GLD16(uS[1] + (kt)*64, lb + 98304 + (b)*16384 + 8192 + tid*16); }

  // ---- fragment read bases (swizzled) ----
  const int l15 = lane & 15, l4 = lane >> 4, l7 = lane & 7;
  const int ko0 = (l4 * 16) ^ (l7 << 4);
  const int ko1 = (64 + l4 * 16) ^ (l7 << 4);
  const int aFB = (wr >> 1) * 16384 + ((wr & 1) * 64 + l15) * 128;
  const int bFB = (wc * 64 + l15) * 128;

#define LDAF(d, b, mf, ko) d = *(const bf16x8*)(lb + (b)*32768 + aFB + (mf)*2048 + (ko))
#define LDGF(d, b, nf, ko) d = *(const bf16x8*)(lb + 65536 + (b)*16384 + bFB + (nf)*2048 + (ko))
#define LDUF(d, b, nf, ko) d = *(const bf16x8*)(lb + 98304 + (b)*16384 + bFB + (nf)*2048 + (ko))

#define MF16(ACC, A, B) \
  _Pragma("unroll") for (int mf = 0; mf < 4; ++mf) \
  _Pragma("unroll") for (int nf = 0; nf < 4; ++nf) \
    ACC[mf][nf] = __builtin_amdgcn_mfma_f32_16x16x32_bf16(A[mf], B[nf], ACC[mf][nf], 0, 0, 0);

  f32x4 accG[4][4], accU[4][4];
  const f32x4 fz = {0.f, 0.f, 0.f, 0.f};
#pragma unroll
  for (int i = 0; i < 4; ++i)
#pragma unroll
    for (int j = 0; j < 4; ++j) { accG[i][j] = fz; accU[i][j] = fz; }

  // prologue: tile0 (A h0,h1, G, U) + tile1 A h0
  STG_A(0, 0, 0); STG_A(0, 1, 0); STG_G(0, 0); STG_U(0, 0); STG_A(1, 0, 1);
  WAITVM(4);
  pbar();

  bf16x8 a0[4], a1[4], g0[4], g1[4], u0[4], u1[4];
  for (int i = 0; i < 8; ++i) {
    const int t1 = 2 * i + 1;
    const int n2 = (2 * i + 2) & 15, n3 = (2 * i + 3) & 15;
    // ph0: buf0 gate k0
#pragma unroll
    for (int f = 0; f < 4; ++f) { LDAF(a0[f], 0, f, ko0); LDGF(g0[f], 0, f, ko0); }
    STG_A(1, 1, t1);
    pbar();
    __builtin_amdgcn_s_setprio(1); MF16(accG, a0, g0); __builtin_amdgcn_s_setprio(0);
    WAITVM(4);
    pbar();
    // ph1: up k0
#pragma unroll
    for (int f = 0; f < 4; ++f) { LDUF(u0[f], 0, f, ko0); LDAF(a1[f], 0, f, ko1); }
    STG_G(1, t1);
    pbar();
    __builtin_amdgcn_s_setprio(1); MF16(accU, a0, u0); __builtin_amdgcn_s_setprio(0);
    pbar();
    // ph2: gate k1
#pragma unroll
    for (int f = 0; f < 4; ++f) { LDGF(g1[f], 0, f, ko1); LDUF(u1[f], 0, f, ko1); }
    STG_U(1, t1);
    pbar();
    __builtin_amdgcn_s_setprio(1); MF16(accG, a1, g1); __builtin_amdgcn_s_setprio(0);
    pbar();
    // ph3: up k1
    STG_A(0, 0, n2);
    pbar();
    __builtin_amdgcn_s_setprio(1); MF16(accU, a1, u1); __builtin_amdgcn_s_setprio(0);
    WAITVM(4);
    pbar();
    // ph4: buf1 gate k0
#pragma unroll
    for (int f = 0; f < 4; ++f) { LDAF(a0[f], 1, f, ko0); LDGF(g0[f], 1, f, ko0); }
    STG_A(0, 1, n2);
    pbar();
    __builtin_amdgcn_s_setprio(1); MF16(accG, a0, g0); __builtin_amdgcn_s_setprio(0);
    WAITVM(4);
    pbar();
    // ph5: up k0
#pragma unroll
    for (int f = 0; f < 4; ++f) { LDUF(u0[f], 1, f, ko0); LDAF(a1[f], 1, f, ko1); }
    STG_G(0, n2);
    pbar();
    __builtin_amdgcn_s_setprio(1); MF16(accU, a0, u0); __builtin_amdgcn_s_setprio(0);
    pbar();
    // ph6: gate k1
#pragma unroll
    for (int f = 0; f < 4; ++f) { LDGF(g1[f], 1, f, ko1); LDUF(u1[f], 1, f, ko1); }
    STG_U(0, n2);
    pbar();
    __builtin_amdgcn_s_setprio(1); MF16(accG, a1, g1); __builtin_amdgcn_s_setprio(0);
    pbar();
    // ph7: up k1
    STG_A(1, 0, n3);
    pbar();
    __builtin_amdgcn_s_setprio(1); MF16(accU, a1, u1); __builtin_amdgcn_s_setprio(0);
    WAITVM(4);
    pbar();
  }
#undef STG_A
#undef STG_G
#undef STG_U
#undef LDAF
#undef LDGF
#undef LDUF

  // epilogue: C/D col=lane&15, row=(lane>>4)*4+j
  const int ct = l4;
#pragma unroll
  for (int mf = 0; mf < 4; ++mf) {
#pragma unroll
    for (int j = 0; j < 4; ++j) {
      int m = wr * 64 + mf * 16 + ct * 4 + j;
      int pr = rowBase + m;
      int pair = pairs[pr];
      float rw = pair >= 0 ? rwf[pair] : 0.f;
      u16* hrow = Hb + (size_t)pr * IDIM + bn0 + wc * 64 + l15;
#pragma unroll
      for (int nf = 0; nf < 4; ++nf) {
        float g = accG[mf][nf][j], u = accU[mf][nf][j];
        float s = g / (1.f + __expf(-g));
        hrow[nf * 16] = f2bf(s * u * rw);
      }
    }
  }
}

// ======================= GEMM2 (8-phase, splitK=2) =======================
// BM=256, BN=256, BK=64; 8 waves = 2M x 4N; per-wave 128x64.
__global__ __launch_bounds__(512, 2) void gemm2_k(
    const u16* __restrict__ Hb, const u16* __restrict__ W2T,
    const int* __restrict__ pairs, const int* __restrict__ meta,
    float* __restrict__ out) {
  // XCD swizzle: nwg = 4*71*2 = 568, q=71, r=0
  int lin = blockIdx.x + 4 * blockIdx.y + 284 * blockIdx.z;
  int xcd = lin & 7, slot = lin >> 3;
  int flat = xcd * 71 + slot;
  int zz = flat / 284, rm = flat % 284;
  int bx = rm / 71, rb = rm % 71;
  if (rb >= meta[24]) return;
  const int e = meta[32 + rb];
  const int bn0 = bx * 256;
  const int kz = zz * 1408;           // splitK chunk: 22 K-tiles
  const int tid = threadIdx.x, lane = tid & 63, w = tid >> 6;
  const int wr = w >> 2, wc = w & 3;
  const int rowBase = rb * 256;

  __shared__ __align__(16) u16 lds[65536];  // A 2x32K | B 2x32K
  char* const lb = (char*)lds;

  const int sr = tid >> 3;
  const int swk = ((tid & 7) << 4) ^ ((sr & 7) << 4);
  const u16* aS[4]; const u16* bS[4];
#pragma unroll
  for (int h = 0; h < 2; ++h)
#pragma unroll
    for (int j = 0; j < 2; ++j) {
      int r = h * 128 + j * 64 + sr;
      aS[h * 2 + j] = Hb + (size_t)(rowBase + r) * IDIM + kz + (swk >> 1);
      bS[h * 2 + j] = W2T + (size_t)e * HDIM * IDIM + (size_t)(bn0 + r) * IDIM + kz + (swk >> 1);
    }

#define STG_A2(b, h, kt) { GLD16(aS[(h)*2+0] + (kt)*64, lb + (b)*32768 + (h)*16384 + tid*16); \
                           GLD16(aS[(h)*2+1] + (kt)*64, lb + (b)*32768 + (h)*16384 + 8192 + tid*16); }
#define STG_B2(b, h, kt) { GLD16(bS[(h)*2+0] + (kt)*64, lb + 65536 + (b)*32768 + (h)*16384 + tid*16); \
                           GLD16(bS[(h)*2+1] + (kt)*64, lb + 65536 + (b)*32768 + (h)*16384 + 8192 + tid*16); }

  const int l15 = lane & 15, l4 = lane >> 4, l7 = lane & 7;
  const int ko0 = (l4 * 16) ^ (l7 << 4);
  const int ko1 = (64 + l4 * 16) ^ (l7 << 4);
  const int aFB = wr * 16384 + l15 * 128;
  const int bFB = (wc >> 1) * 16384 + ((wc & 1) * 64 + l15) * 128;

#define LDAF2(d, b, mf, ko) d = *(const bf16x8*)(lb + (b)*32768 + aFB + (mf)*2048 + (ko))
#define LDBF2(d, b, nf, ko) d = *(const bf16x8*)(lb + 65536 + (b)*32768 + bFB + (nf)*2048 + (ko))

#define MF2(AV, BV, NB) \
  _Pragma("unroll") for (int mf = 0; mf < 8; ++mf) \
  _Pragma("unroll") for (int nn = 0; nn < 2; ++nn) \
    acc[mf][(NB)+nn] = __builtin_amdgcn_mfma_f32_16x16x32_bf16(AV[mf], BV[(NB)+nn], acc[mf][(NB)+nn], 0, 0, 0);

  f32x4 acc[8][4];
  const f32x4 fz = {0.f, 0.f, 0.f, 0.f};
#pragma unroll
  for (int i = 0; i < 8; ++i)
#pragma unroll
    for (int j = 0; j < 4; ++j) acc[i][j] = fz;

  // prologue: tile0 all 4 units + tile1 A h0
  STG_A2(0, 0, 0); STG_A2(0, 1, 0); STG_B2(0, 0, 0); STG_B2(0, 1, 0); STG_A2(1, 0, 1);
  WAITVM(2);
  pbar();

  bf16x8 aK0[8], aK1[8], bK0[4], bK1[4];
  for (int i = 0; i < 11; ++i) {
    const int t1 = 2 * i + 1;
    const int n2 = (2 * i + 2 < 22) ? 2 * i + 2 : 0;
    const int n3 = (2 * i + 3 < 22) ? 2 * i + 3 : 0;
    // ph0: buf0, n0-1 k0
#pragma unroll
    for (int f = 0; f < 8; ++f) LDAF2(aK0[f], 0, f, ko0);
#pragma unroll
    for (int f = 0; f < 4; ++f) LDBF2(bK0[f], 0, f, ko0);
    STG_A2(1, 1, t1);
    pbar();
    __builtin_amdgcn_s_setprio(1); MF2(aK0, bK0, 0); __builtin_amdgcn_s_setprio(0);
    pbar();
    // ph1: n2-3 k0
#pragma unroll
    for (int f = 0; f < 8; ++f) LDAF2(aK1[f], 0, f, ko1);
    STG_B2(1, 0, t1);
    pbar();
    __builtin_amdgcn_s_setprio(1); MF2(aK0, bK0, 2); __builtin_amdgcn_s_setprio(0);
    pbar();
    // ph2: n0-1 k1
#pragma unroll
    for (int f = 0; f < 4; ++f) LDBF2(bK1[f], 0, f, ko1);
    STG_B2(1, 1, t1);
    pbar();
    __builtin_amdgcn_s_setprio(1); MF2(aK1, bK1, 0); __builtin_amdgcn_s_setprio(0);
    pbar();
    // ph3: n2-3 k1
    STG_A2(0, 0, n2);
    pbar();
    __builtin_amdgcn_s_setprio(1); MF2(aK1, bK1, 2); __builtin_amdgcn_s_setprio(0);
    WAITVM(2);
    pbar();
    // ph4: buf1
#pragma unroll
    for (int f = 0; f < 8; ++f) LDAF2(aK0[f], 1, f, ko0);
#pragma unroll
    for (int f = 0; f < 4; ++f) LDBF2(bK0[f], 1, f, ko0);
    STG_A2(0, 1, n2);
    pbar();
    __builtin_amdgcn_s_setprio(1); MF2(aK0, bK0, 0); __builtin_amdgcn_s_setprio(0);
    pbar();
    // ph5
#pragma unroll
    for (int f = 0; f < 8; ++f) LDAF2(aK1[f], 1, f, ko1);
    STG_B2(0, 0, n2);
    pbar();
    __builtin_amdgcn_s_setprio(1); MF2(aK0, bK0, 2); __builtin_amdgcn_s_setprio(0);
    pbar();
    // ph6
#pragma unroll
    for (int f = 0; f < 4; ++f) LDBF2(bK1[f], 1, f, ko1);
    STG_B2(0, 1, n2);
    pbar();
    __builtin_amdgcn_s_setprio(1); MF2(aK1, bK1, 0); __builtin_amdgcn_s_setprio(0);
    pbar();
    // ph7
    STG_A2(1, 0, n3);
    pbar();
    __builtin_amdgcn_s_setprio(1); MF2(aK1, bK1, 2); __builtin_amdgcn_s_setprio(0);
    WAITVM(2);
    pbar();
  }
#undef STG_A2
#undef STG_B2
#undef LDAF2
#undef LDBF2

  const int ct = l4;
#pragma unroll
  for (int mf = 0; mf < 8; ++mf) {
#pragma unroll
    for (int j = 0; j < 4; ++j) {
      int m = wr * 128 + mf * 16 + ct * 4 + j;
      int pair = pairs[rowBase + m];
      if (pair >= 0) {
        float* orow = out + (size_t)(pair >> 1) * HDIM + bn0 + wc * 64 + l15;
#pragma unroll
        for (int nf = 0; nf < 4; ++nf) atomicAdd(orow + nf * 16, acc[mf][nf][j]);
      }
    }
  }
}

extern "C" void kernel_launch(void* const* d_in, const int* in_sizes, int n_in,
                              void* d_out, int out_size, void* d_ws, size_t ws_size,
                              hipStream_t stream) {
  const float* X = (const float*)d_in[0];
  const int* routing = (const int*)d_in[1];
  const float* rwf = (const float*)d_in[2];
  const float* w13 = (const float*)d_in[3];
  const float* w2 = (const float*)d_in[4];
  float* out = (float*)d_out;
  char* ws = (char*)d_ws;

  hipMemsetAsync(d_out, 0, (size_t)T_TOK * HDIM * sizeof(float), stream);
  if (ws_size < WS_NEED) return;  // ws too small -> out stays 0 (visible failure)

  int* meta = (int*)ws;
  int* pairs = (int*)(ws + 1024);
  u16* Xb = (u16*)(ws + XB_OFF);
  u16* W13T = (u16*)(ws + W13T_OFF);
  u16* W2T = (u16*)(ws + W2T_OFF);
  u16* Hb = (u16*)(ws + H_OFF);

  init_meta<<<1, 64, 0, stream>>>(meta);
  count_k<<<NPAIR / 256, 256, 0, stream>>>(routing, meta);
  scan_fill<<<1, 256, 0, stream>>>(meta, pairs);
  scatter_k<<<NPAIR / 256, 256, 0, stream>>>(routing, meta, pairs);
  conv_x<<<(T_TOK * HDIM / 4) / 256, 256, 0, stream>>>(X, Xb);
  transpose_cvt<<<dim3(5632 / 64, 1024 / 64, NEXP), 256, 0, stream>>>(w13, W13T, 1024, 5632);
  transpose_cvt<<<dim3(1024 / 64, 2816 / 64, NEXP), 256, 0, stream>>>(w2, W2T, 2816, 1024);
  gemm1_k<<<dim3(22, MAXRB), 512, 0, stream>>>(Xb, W13T, pairs, meta, rwf, Hb);
  gemm2_k<<<dim3(4, MAXRB, 2), 512, 0, stream>>>(Hb, W2T, pairs, meta, out);
}

// Round 3
// 574.152 us; speedup vs baseline: 1.3423x; 1.1377x over previous
//
#include <hip/hip_runtime.h>

typedef unsigned short u16;
typedef unsigned int u32;
typedef __bf16 bf16x8 __attribute__((ext_vector_type(8)));
typedef float f32x4 __attribute__((ext_vector_type(4)));
typedef u16 u16x4 __attribute__((ext_vector_type(4)));
typedef u16 u16x8 __attribute__((ext_vector_type(8)));

#define T_TOK 8192
#define HDIM 1024
#define IDIM 2816
#define NEXP 8
#define NPAIR (T_TOK * 2)
#define MAXRB 71   // max padded 256-row blocks: 16384/256 + 7

// workspace layout (bytes)
// meta @0 (1K) | pairs @1024 (72704) | inv @73728 (65536) |
#define XB_OFF   (147456u)                       // X bf16 [8192][1024]
#define W13T_OFF (XB_OFF + 16777216u)            // w13^T bf16 [E][5632][1024]  (aliased by part after gemm1)
#define W2T_OFF  (W13T_OFF + 92274688u)          // w2^T bf16 [E][1024][2816]
#define H_OFF    (W2T_OFF + 46137344u)           // h bf16 [71*256][2816]
#define WS_NEED  ((size_t)H_OFF + 102367232u)    // ~257.7 MB

__device__ __forceinline__ u16 f2bf(float f) {
  u32 u = __builtin_bit_cast(u32, f);
  u32 r = u + 0x7fffu + ((u >> 16) & 1u);
  return (u16)(r >> 16);
}

#define GLD16(g, l) __builtin_amdgcn_global_load_lds( \
    (const __attribute__((address_space(1))) void*)(g), \
    (__attribute__((address_space(3))) void*)(l), 16, 0, 0)

#define WAITVM(N) asm volatile("s_waitcnt vmcnt(" #N ")" ::: "memory")

__device__ __forceinline__ void pbar() {
  __builtin_amdgcn_sched_barrier(0);
  asm volatile("" ::: "memory");
  __builtin_amdgcn_s_barrier();
  asm volatile("" ::: "memory");
  __builtin_amdgcn_sched_barrier(0);
}

// ---------------- routing ----------------
__global__ void init_meta(int* meta) {
  if (threadIdx.x < 16) meta[threadIdx.x] = 0;
}

__global__ void count_k(const int* __restrict__ routing, int* __restrict__ meta) {
  int i = blockIdx.x * 256 + threadIdx.x;
  if (i < NPAIR) atomicAdd(&meta[routing[i]], 1);
}

// meta: [0..7] counts, [8..15] cursors, [16..23] startRow, [24] totalRB, [32..102] rbExpert
__global__ void scan_k(int* __restrict__ meta) {
  if (threadIdx.x == 0) {
    int rb = 0;
    for (int e = 0; e < NEXP; ++e) {
      meta[16 + e] = rb * 256;
      int nrb = (meta[e] + 255) >> 8;
      for (int i = 0; i < nrb; ++i) meta[32 + rb + i] = e;
      rb += nrb;
    }
    meta[24] = rb;
  }
}

__global__ void fill_pairs(int* __restrict__ pairs) {
  pairs[blockIdx.x * 256 + threadIdx.x] = -1;
}

__global__ void scatter_k(const int* __restrict__ routing, int* __restrict__ meta,
                          int* __restrict__ pairs, int* __restrict__ inv) {
  int i = blockIdx.x * 256 + threadIdx.x;
  if (i < NPAIR) {
    int e = routing[i];
    int pos = atomicAdd(&meta[8 + e], 1);
    int row = meta[16 + e] + pos;
    pairs[row] = i;
    inv[i] = row;
  }
}

// ---------------- converts ----------------
__global__ void conv_x(const float* __restrict__ in, u16* __restrict__ out) {
  int i = blockIdx.x * 256 + threadIdx.x;   // covers T*H/8
  float4 a = ((const float4*)in)[2 * i];
  float4 b = ((const float4*)in)[2 * i + 1];
  u16x8 o = { f2bf(a.x), f2bf(a.y), f2bf(a.z), f2bf(a.w),
              f2bf(b.x), f2bf(b.y), f2bf(b.z), f2bf(b.w) };
  ((u16x8*)out)[i] = o;
}

// out[c][r] = bf16(in[r][c]); 64x64 tiles, float4 loads, u16x8 stores
__global__ void transpose_cvt(const float* __restrict__ in, u16* __restrict__ out,
                              int R, int C) {
  __shared__ float tile[64][68];
  size_t base = (size_t)blockIdx.z * (size_t)R * (size_t)C;
  in += base; out += base;
  int t = threadIdx.x;
  int r0 = blockIdx.y * 64, c0 = blockIdx.x * 64;
  int lr = t >> 4, lc4 = (t & 15) * 4;
#pragma unroll
  for (int p = 0; p < 4; ++p) {
    float4 v = *(const float4*)&in[(size_t)(r0 + p * 16 + lr) * C + c0 + lc4];
    tile[p * 16 + lr][lc4] = v.x; tile[p * 16 + lr][lc4 + 1] = v.y;
    tile[p * 16 + lr][lc4 + 2] = v.z; tile[p * 16 + lr][lc4 + 3] = v.w;
  }
  __syncthreads();
  int oc = t >> 2, g0 = (t & 3) * 2;
#pragma unroll
  for (int gg = 0; gg < 2; ++gg) {
    int g = g0 + gg;
    u16x8 o = { f2bf(tile[g * 8 + 0][oc]), f2bf(tile[g * 8 + 1][oc]),
                f2bf(tile[g * 8 + 2][oc]), f2bf(tile[g * 8 + 3][oc]),
                f2bf(tile[g * 8 + 4][oc]), f2bf(tile[g * 8 + 5][oc]),
                f2bf(tile[g * 8 + 6][oc]), f2bf(tile[g * 8 + 7][oc]) };
    *(u16x8*)&out[(size_t)(c0 + oc) * R + r0 + g * 8] = o;
  }
}

// ======================= GEMM1 (8-phase, dual-B gate+up) — unchanged control =======================
__global__ __launch_bounds__(512, 2) void gemm1_k(
    const u16* __restrict__ Xb, const u16* __restrict__ W13T,
    const int* __restrict__ pairs, const int* __restrict__ meta,
    const float* __restrict__ rwf, u16* __restrict__ Hb) {
  int lin = blockIdx.x + 22 * blockIdx.y;
  int xcd = lin & 7, slot = lin >> 3;
  int flat = (xcd < 2) ? xcd * 196 + slot : 392 + (xcd - 2) * 195 + slot;
  int bx = flat / 71, rb = flat % 71;
  if (rb >= meta[24]) return;
  const int e = meta[32 + rb];
  const int bn0 = bx * 128;
  const int tid = threadIdx.x, lane = tid & 63, w = tid >> 6;
  const int wr = w >> 1, wc = w & 1;
  const int rowBase = rb * 256;

  __shared__ __align__(16) u16 lds[65536];
  char* const lb = (char*)lds;

  const int sr = tid >> 3;
  const int swk = ((tid & 7) << 4) ^ ((sr & 7) << 4);
  const u16* aS[4];
#pragma unroll
  for (int h = 0; h < 2; ++h)
#pragma unroll
    for (int j = 0; j < 2; ++j) {
      int pr = pairs[rowBase + h * 128 + j * 64 + sr];
      int tok = pr < 0 ? 0 : (pr >> 1);
      aS[h * 2 + j] = Xb + (size_t)tok * HDIM + (swk >> 1);
    }
  const u16* wBase = W13T + (size_t)e * (2 * IDIM) * HDIM;
  const u16* gS[2]; const u16* uS[2];
#pragma unroll
  for (int j = 0; j < 2; ++j) {
    int r = j * 64 + sr;
    gS[j] = wBase + (size_t)(bn0 + r) * HDIM + (swk >> 1);
    uS[j] = wBase + (size_t)(IDIM + bn0 + r) * HDIM + (swk >> 1);
  }

#define STG_A(b, h, kt) { GLD16(aS[(h)*2+0] + (kt)*64, lb + (b)*32768 + (h)*16384 + tid*16); \
                          GLD16(aS[(h)*2+1] + (kt)*64, lb + (b)*32768 + (h)*16384 + 8192 + tid*16); }
#define STG_G(b, kt)    { GLD16(gS[0] + (kt)*64, lb + 65536 + (b)*16384 + tid*16); \
                          GLD16(gS[1] + (kt)*64, lb + 65536 + (b)*16384 + 8192 + tid*16); }
#define STG_U(b, kt)    { GLD16(uS[0] + (kt)*64, lb + 98304 + (b)*16384 + tid*16); \
                          GLD16(uS[1] + (kt)*64, lb + 98304 + (b)*16384 + 8192 + tid*16); }

  const int l15 = lane & 15, l4 = lane >> 4, l7 = lane & 7;
  const int ko0 = (l4 * 16) ^ (l7 << 4);
  const int ko1 = (64 + l4 * 16) ^ (l7 << 4);
  const int aFB = (wr >> 1) * 16384 + ((wr & 1) * 64 + l15) * 128;
  const int bFB = (wc * 64 + l15) * 128;

#define LDAF(d, b, mf, ko) d = *(const bf16x8*)(lb + (b)*32768 + aFB + (mf)*2048 + (ko))
#define LDGF(d, b, nf, ko) d = *(const bf16x8*)(lb + 65536 + (b)*16384 + bFB + (nf)*2048 + (ko))
#define LDUF(d, b, nf, ko) d = *(const bf16x8*)(lb + 98304 + (b)*16384 + bFB + (nf)*2048 + (ko))

#define MF16(ACC, A, B) \
  _Pragma("unroll") for (int mf = 0; mf < 4; ++mf) \
  _Pragma("unroll") for (int nf = 0; nf < 4; ++nf) \
    ACC[mf][nf] = __builtin_amdgcn_mfma_f32_16x16x32_bf16(A[mf], B[nf], ACC[mf][nf], 0, 0, 0);

  f32x4 accG[4][4], accU[4][4];
  const f32x4 fz = {0.f, 0.f, 0.f, 0.f};
#pragma unroll
  for (int i = 0; i < 4; ++i)
#pragma unroll
    for (int j = 0; j < 4; ++j) { accG[i][j] = fz; accU[i][j] = fz; }

  STG_A(0, 0, 0); STG_A(0, 1, 0); STG_G(0, 0); STG_U(0, 0); STG_A(1, 0, 1);
  WAITVM(4);
  pbar();

  bf16x8 a0[4], a1[4], g0[4], g1[4], u0[4], u1[4];
  for (int i = 0; i < 8; ++i) {
    const int t1 = 2 * i + 1;
    const int n2 = (2 * i + 2) & 15, n3 = (2 * i + 3) & 15;
#pragma unroll
    for (int f = 0; f < 4; ++f) { LDAF(a0[f], 0, f, ko0); LDGF(g0[f], 0, f, ko0); }
    STG_A(1, 1, t1);
    pbar();
    __builtin_amdgcn_s_setprio(1); MF16(accG, a0, g0); __builtin_amdgcn_s_setprio(0);
    WAITVM(4);
    pbar();
#pragma unroll
    for (int f = 0; f < 4; ++f) { LDUF(u0[f], 0, f, ko0); LDAF(a1[f], 0, f, ko1); }
    STG_G(1, t1);
    pbar();
    __builtin_amdgcn_s_setprio(1); MF16(accU, a0, u0); __builtin_amdgcn_s_setprio(0);
    pbar();
#pragma unroll
    for (int f = 0; f < 4; ++f) { LDGF(g1[f], 0, f, ko1); LDUF(u1[f], 0, f, ko1); }
    STG_U(1, t1);
    pbar();
    __builtin_amdgcn_s_setprio(1); MF16(accG, a1, g1); __builtin_amdgcn_s_setprio(0);
    pbar();
    STG_A(0, 0, n2);
    pbar();
    __builtin_amdgcn_s_setprio(1); MF16(accU, a1, u1); __builtin_amdgcn_s_setprio(0);
    WAITVM(4);
    pbar();
#pragma unroll
    for (int f = 0; f < 4; ++f) { LDAF(a0[f], 1, f, ko0); LDGF(g0[f], 1, f, ko0); }
    STG_A(0, 1, n2);
    pbar();
    __builtin_amdgcn_s_setprio(1); MF16(accG, a0, g0); __builtin_amdgcn_s_setprio(0);
    WAITVM(4);
    pbar();
#pragma unroll
    for (int f = 0; f < 4; ++f) { LDUF(u0[f], 1, f, ko0); LDAF(a1[f], 1, f, ko1); }
    STG_G(0, n2);
    pbar();
    __builtin_amdgcn_s_setprio(1); MF16(accU, a0, u0); __builtin_amdgcn_s_setprio(0);
    pbar();
#pragma unroll
    for (int f = 0; f < 4; ++f) { LDGF(g1[f], 1, f, ko1); LDUF(u1[f], 1, f, ko1); }
    STG_U(0, n2);
    pbar();
    __builtin_amdgcn_s_setprio(1); MF16(accG, a1, g1); __builtin_amdgcn_s_setprio(0);
    pbar();
    STG_A(1, 0, n3);
    pbar();
    __builtin_amdgcn_s_setprio(1); MF16(accU, a1, u1); __builtin_amdgcn_s_setprio(0);
    WAITVM(4);
    pbar();
  }
#undef STG_A
#undef STG_G
#undef STG_U
#undef LDAF
#undef LDGF
#undef LDUF

  const int ct = l4;
#pragma unroll
  for (int mf = 0; mf < 4; ++mf) {
#pragma unroll
    for (int j = 0; j < 4; ++j) {
      int m = wr * 64 + mf * 16 + ct * 4 + j;
      int pr = rowBase + m;
      int pair = pairs[pr];
      float rw = pair >= 0 ? rwf[pair] : 0.f;
      u16* hrow = Hb + (size_t)pr * IDIM + bn0 + wc * 64 + l15;
#pragma unroll
      for (int nf = 0; nf < 4; ++nf) {
        float g = accG[mf][nf][j], u = accU[mf][nf][j];
        float s = g / (1.f + __expf(-g));
        hrow[nf * 16] = f2bf(s * u * rw);
      }
    }
  }
}

// ======================= GEMM2 (4-phase, BM=BN=128, 2 blocks/CU, no atomics) =======================
__global__ __launch_bounds__(256, 2) void gemm2_k(
    const u16* __restrict__ Hb, const u16* __restrict__ W2T,
    const int* __restrict__ meta, float* __restrict__ part) {
  // nwg = 8 * 142 = 1136, q = 142, r = 0
  int lin = blockIdx.y + 142 * blockIdx.x;
  int xcd = lin & 7, slot = lin >> 3;
  int flat = xcd * 142 + slot;
  int bx = flat / 142, rb2 = flat % 142;
  if (rb2 >= meta[24] * 2) return;
  const int e = meta[32 + (rb2 >> 1)];
  const int bn0 = bx * 128;
  const int tid = threadIdx.x, lane = tid & 63, w = tid >> 6;
  const int wr = w >> 1, wc = w & 1;
  const int rowBase = rb2 * 128;

  __shared__ __align__(16) u16 lds2[32768];   // 64 KiB: A 2x16K | B 2x16K
  char* const lb = (char*)lds2;

  const int sr = tid >> 3;                      // 0..31
  const int swk = ((tid & 7) << 4) ^ ((sr & 7) << 4);
  const u16* aS[4]; const u16* bS[4];
#pragma unroll
  for (int j = 0; j < 4; ++j) {
    aS[j] = Hb + (size_t)(rowBase + j * 32 + sr) * IDIM + (swk >> 1);
    bS[j] = W2T + (size_t)e * HDIM * IDIM + (size_t)(bn0 + j * 32 + sr) * IDIM + (swk >> 1);
  }

#define STG_A2(b, kt) { GLD16(aS[0] + (kt)*64, lb + (b)*16384 + tid*16); \
                        GLD16(aS[1] + (kt)*64, lb + (b)*16384 + 4096 + tid*16); \
                        GLD16(aS[2] + (kt)*64, lb + (b)*16384 + 8192 + tid*16); \
                        GLD16(aS[3] + (kt)*64, lb + (b)*16384 + 12288 + tid*16); }
#define STG_B2(b, kt) { GLD16(bS[0] + (kt)*64, lb + 32768 + (b)*16384 + tid*16); \
                        GLD16(bS[1] + (kt)*64, lb + 32768 + (b)*16384 + 4096 + tid*16); \
                        GLD16(bS[2] + (kt)*64, lb + 32768 + (b)*16384 + 8192 + tid*16); \
                        GLD16(bS[3] + (kt)*64, lb + 32768 + (b)*16384 + 12288 + tid*16); }

  const int l15 = lane & 15, l4 = lane >> 4, l7 = lane & 7;
  const int ko0 = (l4 * 16) ^ (l7 << 4);
  const int ko1 = (64 + l4 * 16) ^ (l7 << 4);
  const int aFB = (wr * 64 + l15) * 128;
  const int bFB = (wc * 64 + l15) * 128;

#define LDAF2(d, b, mf, ko) d = *(const bf16x8*)(lb + (b)*16384 + aFB + (mf)*2048 + (ko))
#define LDBF2(d, b, nf, ko) d = *(const bf16x8*)(lb + 32768 + (b)*16384 + bFB + (nf)*2048 + (ko))

#define MF16v(A, B) \
  _Pragma("unroll") for (int mf = 0; mf < 4; ++mf) \
  _Pragma("unroll") for (int nf = 0; nf < 4; ++nf) \
    acc[mf][nf] = __builtin_amdgcn_mfma_f32_16x16x32_bf16(A[mf], B[nf], acc[mf][nf], 0, 0, 0);

  f32x4 acc[4][4];
  const f32x4 fz = {0.f, 0.f, 0.f, 0.f};
#pragma unroll
  for (int i = 0; i < 4; ++i)
#pragma unroll
    for (int j = 0; j < 4; ++j) acc[i][j] = fz;

  // prologue: A(0,0) B(0,0) A(1,1)  [12 loads]; B(1,1) issued at iter0 ph0
  STG_A2(0, 0); STG_B2(0, 0); STG_A2(1, 1);
  WAITVM(4);
  pbar();

  bf16x8 a0[4], a1[4], b0[4], b1[4];
  for (int i = 0; i < 22; ++i) {
    const int t1 = 2 * i + 1;
    const int nt0 = (2 * i + 2 < 44) ? 2 * i + 2 : 0;
    const int nt1 = (2 * i + 3 < 44) ? 2 * i + 3 : 0;
    // ph0: read ALL buf0 frags; issue B(1,t1); MFMA k0
#pragma unroll
    for (int f = 0; f < 4; ++f) { LDAF2(a0[f], 0, f, ko0); LDAF2(a1[f], 0, f, ko1);
                                  LDBF2(b0[f], 0, f, ko0); LDBF2(b1[f], 0, f, ko1); }
    STG_B2(1, t1);
    pbar();
    __builtin_amdgcn_s_setprio(1); MF16v(a0, b0); __builtin_amdgcn_s_setprio(0);
    pbar();
    // ph1: issue A(0,nt0); MFMA k1
    STG_A2(0, nt0);
    pbar();
    __builtin_amdgcn_s_setprio(1); MF16v(a1, b1); __builtin_amdgcn_s_setprio(0);
    WAITVM(4);
    pbar();
    // ph2: read ALL buf1 frags; issue B(0,nt0); MFMA k0
#pragma unroll
    for (int f = 0; f < 4; ++f) { LDAF2(a0[f], 1, f, ko0); LDAF2(a1[f], 1, f, ko1);
                                  LDBF2(b0[f], 1, f, ko0); LDBF2(b1[f], 1, f, ko1); }
    STG_B2(0, nt0);
    pbar();
    __builtin_amdgcn_s_setprio(1); MF16v(a0, b0); __builtin_amdgcn_s_setprio(0);
    pbar();
    // ph3: issue A(1,nt1); MFMA k1
    STG_A2(1, nt1);
    pbar();
    __builtin_amdgcn_s_setprio(1); MF16v(a1, b1); __builtin_amdgcn_s_setprio(0);
    WAITVM(4);
    pbar();
  }
#undef STG_A2
#undef STG_B2
#undef LDAF2
#undef LDBF2

  WAITVM(0);
  // epilogue: plain fp32 stores to part (pad rows are zeros, never read)
  const int ct = l4;
#pragma unroll
  for (int mf = 0; mf < 4; ++mf) {
#pragma unroll
    for (int j = 0; j < 4; ++j) {
      int m = rowBase + wr * 64 + mf * 16 + ct * 4 + j;
      float* prow = part + (size_t)m * HDIM + bn0 + wc * 64 + l15;
#pragma unroll
      for (int nf = 0; nf < 4; ++nf) prow[nf * 16] = acc[mf][nf][j];
    }
  }
}

// out[t] = part[inv[2t]] + part[inv[2t+1]]
__global__ void reduce_k(const float* __restrict__ part, const int* __restrict__ inv,
                         float* __restrict__ out) {
  int t = blockIdx.x;
  int c = threadIdx.x * 4;
  int r0 = inv[2 * t], r1 = inv[2 * t + 1];
  float4 a = *(const float4*)&part[(size_t)r0 * HDIM + c];
  float4 b = *(const float4*)&part[(size_t)r1 * HDIM + c];
  float4 o = { a.x + b.x, a.y + b.y, a.z + b.z, a.w + b.w };
  *(float4*)&out[(size_t)t * HDIM + c] = o;
}

extern "C" void kernel_launch(void* const* d_in, const int* in_sizes, int n_in,
                              void* d_out, int out_size, void* d_ws, size_t ws_size,
                              hipStream_t stream) {
  const float* X = (const float*)d_in[0];
  const int* routing = (const int*)d_in[1];
  const float* rwf = (const float*)d_in[2];
  const float* w13 = (const float*)d_in[3];
  const float* w2 = (const float*)d_in[4];
  float* out = (float*)d_out;
  char* ws = (char*)d_ws;

  if (ws_size < WS_NEED) {
    hipMemsetAsync(d_out, 0, (size_t)T_TOK * HDIM * sizeof(float), stream);
    return;  // out stays 0 -> visible failure
  }

  int* meta = (int*)ws;
  int* pairs = (int*)(ws + 1024);
  int* inv = (int*)(ws + 73728);
  u16* Xb = (u16*)(ws + XB_OFF);
  u16* W13T = (u16*)(ws + W13T_OFF);
  u16* W2T = (u16*)(ws + W2T_OFF);
  u16* Hb = (u16*)(ws + H_OFF);
  float* part = (float*)(ws + W13T_OFF);   // aliases W13T (dead after gemm1)

  init_meta<<<1, 64, 0, stream>>>(meta);
  count_k<<<NPAIR / 256, 256, 0, stream>>>(routing, meta);
  scan_k<<<1, 64, 0, stream>>>(meta);
  fill_pairs<<<MAXRB, 256, 0, stream>>>(pairs);
  scatter_k<<<NPAIR / 256, 256, 0, stream>>>(routing, meta, pairs, inv);
  conv_x<<<(T_TOK * HDIM / 8) / 256, 256, 0, stream>>>(X, Xb);
  transpose_cvt<<<dim3(5632 / 64, 1024 / 64, NEXP), 256, 0, stream>>>(w13, W13T, 1024, 5632);
  transpose_cvt<<<dim3(1024 / 64, 2816 / 64, NEXP), 256, 0, stream>>>(w2, W2T, 2816, 1024);
  gemm1_k<<<dim3(22, MAXRB), 512, 0, stream>>>(Xb, W13T, pairs, meta, rwf, Hb);
  gemm2_k<<<dim3(8, 2 * MAXRB), 256, 0, stream>>>(Hb, W2T, meta, part);
  reduce_k<<<T_TOK, 256, 0, stream>>>(part, inv, out);
}